// Round 2
// baseline (305.838 us; speedup 1.0000x reference)
//
#include <hip/hip_runtime.h>

// Problem constants: B=4, C1=128, C2=64, H1=W1=128, H2=W2=256, G1=8, G2=16
// BS1=8 (64/block), BS2=16 (256/block), nb=256 blocks/batch.

// ---- workspace layout (float offsets) ----
#define GAP1_OFF 0         // [4*128]  per-channel means of x1
#define GAP2_OFF 512       // [4*64]   per-channel means of x2
#define WSUM_OFF 768       // [64]     row sums of w_f
#define WF2_OFF  832       // [4*64*64] w_f[o,c]*cw[b,c]
#define POS1_OFF 17216     // [4*256*64]
#define POS2_OFF 82752     // [4*256*256]
#define SPA_OFF  344896    // [4*256*256]

// ---------------- K_A: fused per-channel means (gap) + 1x1->1 convs (pos) ----------------
// blocks [0,768): gap work (x1 channels 0..511, x2 channels 512..767)
// blocks [768,2048): pos work (x1 pixels first 256, x2 pixels next 1024)
__global__ __launch_bounds__(256) void k_gp(const float* __restrict__ x1,
                                            const float* __restrict__ x2,
                                            const float* __restrict__ w_p1,
                                            const float* __restrict__ b_p1,
                                            const float* __restrict__ w_p2,
                                            const float* __restrict__ b_p2,
                                            float* __restrict__ ws) {
  int blk = blockIdx.x, t = threadIdx.x;
  if (blk < 768) {
    // ---- gap: one block per channel, float4 streaming reduce ----
    __shared__ float red[4];
    const float4* base;
    int n4; float inv; float* out;
    if (blk < 512) {                 // x1 channels: 4*128
      base = (const float4*)(x1 + (size_t)blk * 16384);
      n4 = 4096; inv = 1.f / 16384.f; out = ws + GAP1_OFF + blk;
    } else {                         // x2 channels: 4*64
      int c = blk - 512;
      base = (const float4*)(x2 + (size_t)c * 65536);
      n4 = 16384; inv = 1.f / 65536.f; out = ws + GAP2_OFF + c;
    }
    float s = 0.f;
    for (int i = t; i < n4; i += 256) { float4 v = base[i]; s += (v.x + v.y) + (v.z + v.w); }
#pragma unroll
    for (int m = 32; m; m >>= 1) s += __shfl_xor(s, m);
    if ((t & 63) == 0) red[t >> 6] = s;
    __syncthreads();
    if (t == 0) *out = (red[0] + red[1] + red[2] + red[3]) * inv;
  } else if (blk < 1024) {
    // ---- pos1: one pixel per thread, dot over 128 channels ----
    int gid = (blk - 768) * 256 + t;         // B*128*128 = 65536
    int b = gid >> 14, hw = gid & 16383;
    int h = hw >> 7, w = hw & 127;
    const float* p = x1 + ((size_t)b << 21) + hw;
    float s = b_p1[0];
#pragma unroll 16
    for (int c = 0; c < 128; ++c) s = fmaf(w_p1[c], p[(size_t)c << 14], s);
    int n = ((h >> 3) << 4) + (w >> 3);
    ws[POS1_OFF + ((b * 256 + n) << 6) + ((h & 7) << 3) + (w & 7)] = s;
  } else {
    // ---- pos2: one pixel per thread, dot over 64 channels ----
    int gid = (blk - 1024) * 256 + t;        // B*256*256 = 262144
    int b = gid >> 16, hw = gid & 65535;
    int h = hw >> 8, w = hw & 255;
    const float* p = x2 + ((size_t)b << 22) + hw;
    float s = b_p2[0];
#pragma unroll 16
    for (int c = 0; c < 64; ++c) s = fmaf(w_p2[c], p[(size_t)c << 16], s);
    int n = ((h >> 4) << 4) + (w >> 4);
    ws[POS2_OFF + ((b * 256 + n) << 8) + ((h & 15) << 4) + (w & 15)] = s;
  }
}

// ---------------- K2: channel-attention weights + fused conv matrix ----------------
__global__ __launch_bounds__(256) void k_small(const float* __restrict__ w_c1,
                                               const float* __restrict__ b_c1,
                                               const float* __restrict__ w_c2,
                                               const float* __restrict__ b_c2,
                                               const float* __restrict__ w_f,
                                               float* __restrict__ ws) {
  __shared__ float cw_s[256];   // [b][channel 0..63]
  int t = threadIdx.x;
  if (t < 32) {
    int b = t >> 3, g = t & 7;
    const float* g1 = ws + GAP1_OFF + (b * 8 + g) * 16;
    const float* g2 = ws + GAP2_OFF + (b * 8 + g) * 8;
    float m1[8], m2[8];
    for (int o = 0; o < 8; ++o) {
      float s = b_c1[o];
      for (int c = 0; c < 16; ++c) s = fmaf(w_c1[o * 16 + c], g1[c], s);
      m1[o] = fmaxf(s, 0.f);
    }
    float ss = 0.f;
    for (int p = 0; p < 8; ++p) {
      float s = b_c2[p];
      for (int c = 0; c < 8; ++c) s = fmaf(w_c2[p * 8 + c], g2[c], s);
      float r = fmaxf(s, 0.f);
      m2[p] = r; ss = fmaf(r, r, ss);
    }
    float lg[8], mx = -1e30f;
    for (int o = 0; o < 8; ++o) { lg[o] = m1[o] * ss; mx = fmaxf(mx, lg[o]); }
    float se = 0.f;
    for (int o = 0; o < 8; ++o) { lg[o] = __expf(lg[o] - mx); se += lg[o]; }
    float inv = 1.f / se;
    for (int o = 0; o < 8; ++o) cw_s[b * 64 + g * 8 + o] = lg[o] * inv;
  }
  __syncthreads();
  if (t < 64) {
    float s = 0.f;
    for (int c = 0; c < 64; ++c) s += w_f[t * 64 + c];
    ws[WSUM_OFF + t] = s;
  }
  for (int i = t; i < 16384; i += 256) {
    int rem = i & 4095;        // o*64+c  (== w_f flat index)
    int b = i >> 12, c = rem & 63;
    ws[WF2_OFF + i] = w_f[rem] * cw_s[b * 64 + c];
  }
}

// ---------------- K4: per-block rank-1 spatial attention ----------------
__global__ __launch_bounds__(256) void k_attn(const float* __restrict__ w_lin,
                                              const float* __restrict__ b_lin,
                                              float* __restrict__ ws) {
  __shared__ float P1[64], V[256], A[256], Sq[256], Mq[256], rmx[4], rmn[4];
  int bn = blockIdx.x, t = threadIdx.x;
  if (t < 64) P1[t] = ws[POS1_OFF + bn * 64 + t];
  float a = ws[POS2_OFF + bn * 256 + t];
  A[t] = a;
  __syncthreads();
  // x1t[t] = w_lin[t,:] . pos1 + b_lin[t]
  float v = b_lin[t];
  const float* wr = w_lin + t * 64;
#pragma unroll
  for (int c = 0; c < 64; ++c) v = fmaf(wr[c], P1[c], v);
  V[t] = v;
  // block-wide max/min of x1t (rank-1 softmax: rowmax = a>0 ? a*vmax : a*vmin)
  float vmax = v, vmin = v;
#pragma unroll
  for (int m = 32; m; m >>= 1) {
    vmax = fmaxf(vmax, __shfl_xor(vmax, m));
    vmin = fminf(vmin, __shfl_xor(vmin, m));
  }
  if ((t & 63) == 0) { rmx[t >> 6] = vmax; rmn[t >> 6] = vmin; }
  __syncthreads();
  vmax = fmaxf(fmaxf(rmx[0], rmx[1]), fmaxf(rmx[2], rmx[3]));
  vmin = fminf(fminf(rmn[0], rmn[1]), fminf(rmn[2], rmn[3]));
  // pass 1: softmax denominator for row q=t
  float m = (a > 0.f) ? a * vmax : a * vmin;
  float den = 0.f;
#pragma unroll 8
  for (int k = 0; k < 256; ++k) den += __expf(fmaf(a, V[k], -m));
  Sq[t] = a / den; Mq[t] = m;
  __syncthreads();
  // pass 2: weighted[k=t] = sum_q (a_q/den_q) * exp(a_q*v_k - m_q)
  float acc = 0.f;
#pragma unroll 8
  for (int q = 0; q < 256; ++q) acc = fmaf(Sq[q], __expf(fmaf(A[q], v, -Mq[q])), acc);
  ws[SPA_OFF + bn * 256 + t] = acc;
}

// ---------------- K5: fused 1x1 conv (folded cw) + BN + ReLU ----------------
// M (per-batch 64x64) is block-uniform -> read through uniform pointer so the
// compiler emits s_load + v_fmac(s,v) instead of LDS broadcast reads
// (R1 post-mortem: LDS-issue-bound at 75us, 16 waves x 1024 ds_read_b128).
__global__ __launch_bounds__(256) void k_final(const float* __restrict__ x2,
                                               const float* __restrict__ b_f,
                                               const float* __restrict__ gm_,
                                               const float* __restrict__ bt_,
                                               const float* __restrict__ ws,
                                               float* __restrict__ out) {
  int t = threadIdx.x;
  int gid = blockIdx.x * 256 + t;          // B*65536 pixels
  int b = blockIdx.x >> 8;                 // wave-uniform (256 blocks per batch)
  int pix = gid & 65535;
  const float* __restrict__ M = ws + WF2_OFF + (b << 12);   // uniform base
  const float* px = x2 + ((size_t)b << 22) + pix;
  float x[64];
#pragma unroll
  for (int c = 0; c < 64; ++c) x[c] = px[(size_t)c << 16];
  float spa = ws[SPA_OFF + gid];
  const float kbn = 0.99999500003749969f;  // 1/sqrt(1+1e-5)
  float* po = out + ((size_t)b << 22) + pix;
#pragma unroll 4
  for (int o = 0; o < 64; ++o) {
    float acc = fmaf(spa, ws[WSUM_OFF + o], b_f[o]);   // uniform -> s_load
    const float* __restrict__ Mo = M + o * 64;
    float a0 = 0.f, a1 = 0.f, a2 = 0.f, a3 = 0.f;
#pragma unroll
    for (int c = 0; c < 64; c += 4) {
      a0 = fmaf(Mo[c + 0], x[c + 0], a0);
      a1 = fmaf(Mo[c + 1], x[c + 1], a1);
      a2 = fmaf(Mo[c + 2], x[c + 2], a2);
      a3 = fmaf(Mo[c + 3], x[c + 3], a3);
    }
    acc += (a0 + a1) + (a2 + a3);
    float r = fmaf(acc * kbn, gm_[o], bt_[o]);
    po[(size_t)o << 16] = fmaxf(r, 0.f);
  }
}

extern "C" void kernel_launch(void* const* d_in, const int* in_sizes, int n_in,
                              void* d_out, int out_size, void* d_ws, size_t ws_size,
                              hipStream_t stream) {
  const float* x1   = (const float*)d_in[0];
  const float* x2   = (const float*)d_in[1];
  const float* w_c1 = (const float*)d_in[2];
  const float* b_c1 = (const float*)d_in[3];
  const float* w_c2 = (const float*)d_in[4];
  const float* b_c2 = (const float*)d_in[5];
  const float* w_p1 = (const float*)d_in[6];
  const float* b_p1 = (const float*)d_in[7];
  const float* w_p2 = (const float*)d_in[8];
  const float* b_p2 = (const float*)d_in[9];
  const float* w_lin= (const float*)d_in[10];
  const float* b_lin= (const float*)d_in[11];
  const float* w_f  = (const float*)d_in[12];
  const float* b_f  = (const float*)d_in[13];
  const float* gmm  = (const float*)d_in[14];
  const float* btt  = (const float*)d_in[15];
  float* ws  = (float*)d_ws;
  float* out = (float*)d_out;

  hipLaunchKernelGGL(k_gp,    dim3(2048), dim3(256), 0, stream, x1, x2, w_p1, b_p1, w_p2, b_p2, ws);
  hipLaunchKernelGGL(k_small, dim3(1),    dim3(256), 0, stream, w_c1, b_c1, w_c2, b_c2, w_f, ws);
  hipLaunchKernelGGL(k_attn,  dim3(1024), dim3(256), 0, stream, w_lin, b_lin, ws);
  hipLaunchKernelGGL(k_final, dim3(1024), dim3(256), 0, stream, x2, b_f, gmm, btt, ws, out);
}

// Round 4
// 251.055 us; speedup vs baseline: 1.2182x; 1.2182x over previous
//
#include <hip/hip_runtime.h>

// B=4, C1=128, C2=64, H1=W1=128, H2=W2=256, G1=8, G2=16, BS1=8, BS2=16, nb=256.

// ---- workspace layout (float offsets) ----
#define GAP1_OFF 0         // [512]   per-channel means of x1  [b*128+c]
#define GAP2_OFF 512       // [256]   per-channel means of x2  [b*64+c]
#define P2_OFF   768       // [64]    wsum[o]*kbn*gm[o]
#define P3_OFF   832       // [64]    b_f[o]*kbn*gm[o] + bt[o]
#define WF2T_OFF 896       // [4*64*64=16384] BN-folded, transposed: [b][c][o]
#define POS1_OFF 17280     // [4*256*64 = 65536]
#define POS2_OFF 82816     // [4*256*256 = 262144]
#define SPA_OFF  344960    // [4*256*256 = 262144]
// total 607104 floats = 2.32 MB  (R3 bug: POS2_OFF was 33664, overlapping POS1)

// ---------------- K1: gap (channel means) + pos (1x1->1 convs), one launch ----------------
__global__ __launch_bounds__(256) void k_gp(const float* __restrict__ x1,
                                            const float* __restrict__ x2,
                                            const float* __restrict__ w_p1,
                                            const float* __restrict__ b_p1,
                                            const float* __restrict__ w_p2,
                                            const float* __restrict__ b_p2,
                                            float* __restrict__ ws) {
  int blk = blockIdx.x, t = threadIdx.x;
  if (blk < 768) {
    __shared__ float red[4];
    const float4* base;
    int n4; float inv; float* out;
    if (blk < 512) {                 // x1 channels: 4*128
      base = (const float4*)(x1 + (size_t)blk * 16384);
      n4 = 4096; inv = 1.f / 16384.f; out = ws + GAP1_OFF + blk;
    } else {                         // x2 channels: 4*64
      int c = blk - 512;
      base = (const float4*)(x2 + (size_t)c * 65536);
      n4 = 16384; inv = 1.f / 65536.f; out = ws + GAP2_OFF + c;
    }
    float s = 0.f;
    for (int i = t; i < n4; i += 256) { float4 v = base[i]; s += (v.x + v.y) + (v.z + v.w); }
#pragma unroll
    for (int m = 32; m; m >>= 1) s += __shfl_xor(s, m);
    if ((t & 63) == 0) red[t >> 6] = s;
    __syncthreads();
    if (t == 0) *out = (red[0] + red[1] + red[2] + red[3]) * inv;
  } else if (blk < 896) {
    // pos1: 2 consecutive pixels per thread (w0 even -> same 8-wide block)
    int gid = (blk - 768) * 256 + t;         // [0, 32768)
    int b = gid >> 13;
    int hw = (gid << 1) & 16383;
    int h = hw >> 7, w0 = hw & 127;
    const float* p = x1 + ((size_t)b << 21) + hw;
    float bb = b_p1[0];
    float s0 = bb, s1 = 0.f;
#pragma unroll 8
    for (int c = 0; c < 128; ++c) {
      float2 v = *(const float2*)(p + ((size_t)c << 14));
      float wc = w_p1[c];
      s0 = fmaf(wc, v.x, s0);
      s1 = fmaf(wc, v.y, s1);
    }
    s1 += bb;
    int n = ((h >> 3) << 4) + (w0 >> 3);
    float2 o2; o2.x = s0; o2.y = s1;
    *(float2*)&ws[POS1_OFF + ((b * 256 + n) << 6) + ((h & 7) << 3) + (w0 & 7)] = o2;
  } else {
    // pos2: 4 consecutive pixels per thread (w0 mult of 4 -> same 16-wide block)
    int gid = (blk - 896) * 256 + t;         // [0, 65536)
    int b = gid >> 14;
    int hw = (gid << 2) & 65535;
    int h = hw >> 8, w0 = hw & 255;
    const float* p = x2 + ((size_t)b << 22) + hw;
    float bb = b_p2[0];
    float s0 = bb, s1 = 0.f, s2 = 0.f, s3 = 0.f;
#pragma unroll 8
    for (int c = 0; c < 64; ++c) {
      float4 v = *(const float4*)(p + ((size_t)c << 16));
      float wc = w_p2[c];
      s0 = fmaf(wc, v.x, s0); s1 = fmaf(wc, v.y, s1);
      s2 = fmaf(wc, v.z, s2); s3 = fmaf(wc, v.w, s3);
    }
    s1 += bb; s2 += bb; s3 += bb;
    int n = ((h >> 4) << 4) + (w0 >> 4);
    float4 o4; o4.x = s0; o4.y = s1; o4.z = s2; o4.w = s3;
    *(float4*)&ws[POS2_OFF + ((b * 256 + n) << 8) + ((h & 15) << 4) + (w0 & 15)] = o4;
  }
}

// ---------------- K2: channel attention + BN-folded transposed conv matrix ----------------
__global__ __launch_bounds__(256) void k_small(const float* __restrict__ w_c1,
                                               const float* __restrict__ b_c1,
                                               const float* __restrict__ w_c2,
                                               const float* __restrict__ b_c2,
                                               const float* __restrict__ w_f,
                                               const float* __restrict__ b_f,
                                               const float* __restrict__ gm,
                                               const float* __restrict__ bt,
                                               float* __restrict__ ws) {
  __shared__ float cw_s[256];   // [b][c2 channel]
  int t = threadIdx.x;
  const float kbn = 0.99999500003749969f;  // 1/sqrt(1+1e-5)
  if (t < 32) {
    int b = t >> 3, g = t & 7;
    const float* g1 = ws + GAP1_OFF + (b * 8 + g) * 16;
    const float* g2 = ws + GAP2_OFF + (b * 8 + g) * 8;
    float m1[8], m2[8];
    for (int o = 0; o < 8; ++o) {
      float s = b_c1[o];
      for (int c = 0; c < 16; ++c) s = fmaf(w_c1[o * 16 + c], g1[c], s);
      m1[o] = fmaxf(s, 0.f);
    }
    float ss = 0.f;
    for (int p = 0; p < 8; ++p) {
      float s = b_c2[p];
      for (int c = 0; c < 8; ++c) s = fmaf(w_c2[p * 8 + c], g2[c], s);
      float r = fmaxf(s, 0.f);
      m2[p] = r; ss = fmaf(r, r, ss);
    }
    float lg[8], mx = -1e30f;
    for (int o = 0; o < 8; ++o) { lg[o] = m1[o] * ss; mx = fmaxf(mx, lg[o]); }
    float se = 0.f;
    for (int o = 0; o < 8; ++o) { lg[o] = __builtin_amdgcn_exp2f((lg[o] - mx) * 1.44269504088896f); se += lg[o]; }
    float inv = 1.f / se;
    for (int o = 0; o < 8; ++o) cw_s[b * 64 + g * 8 + o] = lg[o] * inv;
  }
  __syncthreads();
  if (t < 64) {
    float s = 0.f;
    for (int c = 0; c < 64; ++c) s += w_f[t * 64 + c];
    float A = kbn * gm[t];
    ws[P2_OFF + t] = s * A;
    ws[P3_OFF + t] = fmaf(b_f[t], A, bt[t]);
  }
  for (int i = t; i < 16384; i += 256) {
    int b = i >> 12, rem = i & 4095;
    int c = rem >> 6, o = rem & 63;
    ws[WF2T_OFF + i] = w_f[o * 64 + c] * cw_s[b * 64 + c] * (kbn * gm[o]);
  }
}

// ---------------- K3: per-block rank-1 spatial attention ----------------
__global__ __launch_bounds__(256) void k_attn(const float* __restrict__ w_lin,
                                              const float* __restrict__ b_lin,
                                              const float* __restrict__ wsr,
                                              float* __restrict__ wsw) {
  __shared__ float P1[64], V[256], A2[256], Sq[256], Mq[256];
  __shared__ float rmx[4], rmn[4];
  const float L2E = 1.44269504088896f;
  int bn = blockIdx.x, t = threadIdx.x;
  if (t < 64) P1[t] = wsr[POS1_OFF + bn * 64 + t];
  float a = wsr[POS2_OFF + bn * 256 + t];
  float a2 = a * L2E;
  A2[t] = a2;
  __syncthreads();
  float v = b_lin[t];
  const float* wr = w_lin + t * 64;
#pragma unroll 16
  for (int c = 0; c < 64; ++c) v = fmaf(wr[c], P1[c], v);
  V[t] = v;
  float vmax = v, vmin = v;
#pragma unroll
  for (int m = 32; m; m >>= 1) {
    vmax = fmaxf(vmax, __shfl_xor(vmax, m));
    vmin = fminf(vmin, __shfl_xor(vmin, m));
  }
  if ((t & 63) == 0) { rmx[t >> 6] = vmax; rmn[t >> 6] = vmin; }
  __syncthreads();
  vmax = fmaxf(fmaxf(rmx[0], rmx[1]), fmaxf(rmx[2], rmx[3]));
  vmin = fminf(fminf(rmn[0], rmn[1]), fminf(rmn[2], rmn[3]));
  // pass 1: denominator, exp2 domain, 4 partials
  float m2 = (a2 > 0.f) ? a2 * vmax : a2 * vmin;
  float d0 = 0.f, d1 = 0.f, d2 = 0.f, d3 = 0.f;
#pragma unroll 4
  for (int k = 0; k < 256; k += 4) {
    float4 vv = *(float4*)&V[k];
    d0 += __builtin_amdgcn_exp2f(fmaf(a2, vv.x, -m2));
    d1 += __builtin_amdgcn_exp2f(fmaf(a2, vv.y, -m2));
    d2 += __builtin_amdgcn_exp2f(fmaf(a2, vv.z, -m2));
    d3 += __builtin_amdgcn_exp2f(fmaf(a2, vv.w, -m2));
  }
  float den = (d0 + d1) + (d2 + d3);
  Sq[t] = a / den; Mq[t] = m2;
  __syncthreads();
  // pass 2: weighted[k=t] = sum_q Sq[q]*exp2(A2[q]*v - Mq[q])
  float c0 = 0.f, c1 = 0.f, c2 = 0.f, c3 = 0.f;
#pragma unroll 4
  for (int q = 0; q < 256; q += 4) {
    float4 aq = *(float4*)&A2[q];
    float4 sq = *(float4*)&Sq[q];
    float4 mq = *(float4*)&Mq[q];
    c0 = fmaf(sq.x, __builtin_amdgcn_exp2f(fmaf(aq.x, v, -mq.x)), c0);
    c1 = fmaf(sq.y, __builtin_amdgcn_exp2f(fmaf(aq.y, v, -mq.y)), c1);
    c2 = fmaf(sq.z, __builtin_amdgcn_exp2f(fmaf(aq.z, v, -mq.z)), c2);
    c3 = fmaf(sq.w, __builtin_amdgcn_exp2f(fmaf(aq.w, v, -mq.w)), c3);
  }
  wsw[SPA_OFF + bn * 256 + t] = (c0 + c1) + (c2 + c3);
}

// ---------------- K4: fused 1x1 conv + BN + ReLU, 8o x 8pix register tile ----------------
// Per block: 256-pixel tile x all 64 outputs of one batch. Xt (64KB) + Mt (16KB) = 80KB LDS
// -> 2 blocks/CU. 16 FMA per ds_read_b128 (R1 was 4:1 -> LDS-bound; R2 global-M latency-bound).
__global__ __launch_bounds__(256) void k_final(const float* __restrict__ x2,
                                               const float* __restrict__ ws,
                                               float* __restrict__ out) {
  __shared__ float Xt[64 * 256];   // [c][pix]
  __shared__ float Mt[64 * 64];    // [c][o], BN-folded
  int t = threadIdx.x;
  int blk = blockIdx.x;
  int b = blk >> 8;
  int p0 = (blk & 255) << 8;
  const float* xg = x2 + ((size_t)b << 22) + p0;
#pragma unroll
  for (int i = 0; i < 16; ++i) {
    int f4 = i * 256 + t;
    int c = f4 >> 6, col = (f4 & 63) << 2;
    float4 v = *(const float4*)(xg + ((size_t)c << 16) + col);
    *(float4*)&Xt[c * 256 + col] = v;
  }
  const float* mg = ws + WF2T_OFF + (b << 12);
#pragma unroll
  for (int i = 0; i < 4; ++i) {
    int f4 = i * 256 + t;
    *(float4*)&Mt[f4 << 2] = *(const float4*)(mg + ((size_t)f4 << 2));
  }
  __syncthreads();
  int og = (t >> 5) << 3;   // output-channel base (8 groups)
  int pg = (t & 31) << 3;   // pixel base within tile (32 groups)
  float acc[8][8];
#pragma unroll
  for (int i = 0; i < 8; ++i)
#pragma unroll
    for (int j = 0; j < 8; ++j) acc[i][j] = 0.f;
#pragma unroll 4
  for (int c = 0; c < 64; ++c) {
    float4 xa = *(float4*)&Xt[c * 256 + pg];
    float4 xb = *(float4*)&Xt[c * 256 + pg + 4];
    float4 ma = *(float4*)&Mt[(c << 6) + og];
    float4 mb = *(float4*)&Mt[(c << 6) + og + 4];
    float xs[8] = {xa.x, xa.y, xa.z, xa.w, xb.x, xb.y, xb.z, xb.w};
    float ms[8] = {ma.x, ma.y, ma.z, ma.w, mb.x, mb.y, mb.z, mb.w};
#pragma unroll
    for (int i = 0; i < 8; ++i)
#pragma unroll
      for (int j = 0; j < 8; ++j)
        acc[i][j] = fmaf(ms[i], xs[j], acc[i][j]);
  }
  const float* sp = ws + SPA_OFF + (b << 16) + p0 + pg;
  float4 sa = *(const float4*)sp;
  float4 sb = *(const float4*)(sp + 4);
  float spa[8] = {sa.x, sa.y, sa.z, sa.w, sb.x, sb.y, sb.z, sb.w};
  float* outp = out + ((size_t)b << 22) + p0 + pg;
#pragma unroll
  for (int i = 0; i < 8; ++i) {
    int o = og + i;
    float p2 = ws[P2_OFF + o];
    float p3 = ws[P3_OFF + o];
    float r[8];
#pragma unroll
    for (int j = 0; j < 8; ++j)
      r[j] = fmaxf(fmaf(spa[j], p2, acc[i][j] + p3), 0.f);
    float4 r0; r0.x = r[0]; r0.y = r[1]; r0.z = r[2]; r0.w = r[3];
    float4 r1; r1.x = r[4]; r1.y = r[5]; r1.z = r[6]; r1.w = r[7];
    float* po = outp + ((size_t)o << 16);
    *(float4*)po = r0;
    *(float4*)(po + 4) = r1;
  }
}

extern "C" void kernel_launch(void* const* d_in, const int* in_sizes, int n_in,
                              void* d_out, int out_size, void* d_ws, size_t ws_size,
                              hipStream_t stream) {
  const float* x1   = (const float*)d_in[0];
  const float* x2   = (const float*)d_in[1];
  const float* w_c1 = (const float*)d_in[2];
  const float* b_c1 = (const float*)d_in[3];
  const float* w_c2 = (const float*)d_in[4];
  const float* b_c2 = (const float*)d_in[5];
  const float* w_p1 = (const float*)d_in[6];
  const float* b_p1 = (const float*)d_in[7];
  const float* w_p2 = (const float*)d_in[8];
  const float* b_p2 = (const float*)d_in[9];
  const float* w_lin= (const float*)d_in[10];
  const float* b_lin= (const float*)d_in[11];
  const float* w_f  = (const float*)d_in[12];
  const float* b_f  = (const float*)d_in[13];
  const float* gmm  = (const float*)d_in[14];
  const float* btt  = (const float*)d_in[15];
  float* ws  = (float*)d_ws;
  float* out = (float*)d_out;

  hipLaunchKernelGGL(k_gp,    dim3(1152), dim3(256), 0, stream, x1, x2, w_p1, b_p1, w_p2, b_p2, ws);
  hipLaunchKernelGGL(k_small, dim3(1),    dim3(256), 0, stream, w_c1, b_c1, w_c2, b_c2, w_f, b_f, gmm, btt, ws);
  hipLaunchKernelGGL(k_attn,  dim3(1024), dim3(256), 0, stream, w_lin, b_lin, ws, ws);
  hipLaunchKernelGGL(k_final, dim3(1024), dim3(256), 0, stream, x2, ws, out);
}